// Round 2
// baseline (14722.606 us; speedup 1.0000x reference)
//
#include <hip/hip_runtime.h>

#define HSTEPS 8640
#define HID 128
#define BATCH 16
#define NTHR 768

typedef _Float16 h16;
typedef __attribute__((ext_vector_type(2))) _Float16 h16x2;
typedef __attribute__((ext_vector_type(8))) _Float16 h16x8;

#if __has_builtin(__builtin_amdgcn_fdot2)
#define FDOT2(a, b, c) __builtin_amdgcn_fdot2((a), (b), (c), false)
#else
static __device__ __forceinline__ float FDOT2(h16x2 a, h16x2 b, float c) {
    return c + (float)a[0] * (float)b[0] + (float)a[1] * (float)b[1];
}
#endif

static __device__ __forceinline__ float sigm(float x) {
    return __builtin_amdgcn_rcpf(1.0f + __expf(-x));
}
static __device__ __forceinline__ float tanh_f(float x) {
    float ax = __builtin_fabsf(x);
    float e = __expf(2.0f * ax);
    float r = 1.0f - 2.0f * __builtin_amdgcn_rcpf(e + 1.0f);
    return __builtin_copysignf(r, x);
}
static __device__ __forceinline__ float lstm_act(float gi, float gf, float gg,
                                                 float go, float& cst) {
    float si = sigm(gi), sf = sigm(gf), so = sigm(go);
    float tg = tanh_f(gg);
    cst = __builtin_fmaf(sf, cst, si * tg);
    return so * tanh_f(cst);
}

// dot of two register-resident rows (64 f16-pairs each) vs shared h vector
static __device__ __forceinline__ void dot2rows(const h16* hsh, const h16x2* wA,
                                                const h16x2* wB, float initA,
                                                float initB, float& outA,
                                                float& outB) {
    float a0 = initA, a1 = 0.f, a2 = 0.f, a3 = 0.f;
    float b0 = initB, b1 = 0.f, b2 = 0.f, b3 = 0.f;
#pragma unroll
    for (int i = 0; i < 16; ++i) {
        h16x8 hv = *(const h16x8*)(&hsh[i * 8]);
        h16x2 p0 = {hv[0], hv[1]}, p1 = {hv[2], hv[3]};
        h16x2 p2 = {hv[4], hv[5]}, p3 = {hv[6], hv[7]};
        a0 = FDOT2(wA[4 * i + 0], p0, a0);
        a1 = FDOT2(wA[4 * i + 1], p1, a1);
        a2 = FDOT2(wA[4 * i + 2], p2, a2);
        a3 = FDOT2(wA[4 * i + 3], p3, a3);
        b0 = FDOT2(wB[4 * i + 0], p0, b0);
        b1 = FDOT2(wB[4 * i + 1], p1, b1);
        b2 = FDOT2(wB[4 * i + 2], p2, b2);
        b3 = FDOT2(wB[4 * i + 3], p3, b3);
    }
    outA = (a0 + a1) + (a2 + a3);
    outB = (b0 + b1) + (b2 + b3);
}

// One block per batch. 768 threads = 3 groups x 256; group g owns one weight
// matrix (0: Whh0, 1: Wih1, 2: Whh1), 2 rows/thread => 128 weight VGPRs/thread
// (fits the 3-waves/SIMD architected budget; no spill).
// Phase A: grp0 (Whh0@h0) and grp2 (Whh1@h1) run concurrently.
// act0 on threads 256..383; act1+fc on threads 0..127 (they hold c-states).
__global__ __launch_bounds__(NTHR, 3) void lstm2_kernel(
    const float* __restrict__ y0, const float* __restrict__ h0in,
    const float* __restrict__ c0in, const float* __restrict__ Wih0,
    const float* __restrict__ Whh0, const float* __restrict__ bih0,
    const float* __restrict__ bhh0, const float* __restrict__ Wih1,
    const float* __restrict__ Whh1, const float* __restrict__ bih1,
    const float* __restrict__ bhh1, const float* __restrict__ fcw,
    const float* __restrict__ fcb, float* __restrict__ out) {
    const int b = blockIdx.x;
    const int t = threadIdx.x;

    __shared__ __align__(16) h16 h0h[HID];
    __shared__ __align__(16) h16 h1h[HID];
    __shared__ float gbuf0[4 * HID];  // layer-0 gates
    __shared__ float g1a[4 * HID];    // Wih1 @ h0n (+bias1)
    __shared__ float g1b[4 * HID];    // Whh1 @ h1
    __shared__ float ypart[2];

    const int grp = t >> 8;
    const int local = t & 255;
    const int r0 = local, r1 = local + 256;

    const float* Wsrc = (grp == 0) ? Whh0 : (grp == 1 ? Wih1 : Whh1);
    h16x2 wA[64], wB[64];
#pragma unroll
    for (int i = 0; i < 64; ++i) {
        float2 a = *(const float2*)(Wsrc + r0 * HID + 2 * i);
        wA[i] = h16x2{(h16)a.x, (h16)a.y};
        float2 c = *(const float2*)(Wsrc + r1 * HID + 2 * i);
        wB[i] = h16x2{(h16)c.x, (h16)c.y};
    }
    float biasA = 0.f, biasB = 0.f, wihA = 0.f, wihB = 0.f;
    if (grp == 0) {
        biasA = bih0[r0] + bhh0[r0];
        biasB = bih0[r1] + bhh0[r1];
        wihA = Wih0[r0];
        wihB = Wih0[r1];
    } else if (grp == 1) {
        biasA = bih1[r0] + bhh1[r0];
        biasB = bih1[r1] + bhh1[r1];
    }
    const float fcb_ = fcb[0];

    float cst = 0.f, fcwj = 0.f;
    if (t < HID) {  // act1 threads: own c1[t]
        cst = c0in[(BATCH + b) * HID + t];
        h1h[t] = (h16)h0in[(BATCH + b) * HID + t];
        fcwj = fcw[t];
    } else if (t >= 256 && t < 256 + HID) {  // act0 threads: own c0[j]
        int j = t - 256;
        cst = c0in[b * HID + j];
        h0h[j] = (h16)h0in[b * HID + j];
    }
    if (t == 0) {
        ypart[0] = y0[b] - fcb_;  // so step-0 y equals y0
        ypart[1] = 0.f;
    }
    __syncthreads();

    float* outb = out + (size_t)b * HSTEPS;

#pragma unroll 1
    for (int step = 0; step < HSTEPS; ++step) {
        float y = ypart[0] + ypart[1] + fcb_;
        if (t == 0 && step > 0) outb[step - 1] = y;

        if (grp == 0) {  // Whh0 @ h0 (+bias0 + Wih0*y)
            float gA, gB;
            dot2rows(h0h, wA, wB, __builtin_fmaf(wihA, y, biasA),
                     __builtin_fmaf(wihB, y, biasB), gA, gB);
            gbuf0[r0] = gA;
            gbuf0[r1] = gB;
        } else if (grp == 2) {  // Whh1 @ h1 (concurrent: h1 is from prev step)
            float gA, gB;
            dot2rows(h1h, wA, wB, 0.f, 0.f, gA, gB);
            g1b[r0] = gA;
            g1b[r1] = gB;
        }
        __syncthreads();  // B1: gbuf0 + g1b ready

        float pgi = 0.f, pgf = 0.f, pgg = 0.f, pgo = 0.f;
        if (t < HID) {  // prefetch Whh1 partials off the critical path
            pgi = g1b[t];
            pgf = g1b[t + 128];
            pgg = g1b[t + 256];
            pgo = g1b[t + 384];
        }
        if (t >= 256 && t < 256 + HID) {  // act0
            int j = t - 256;
            float h = lstm_act(gbuf0[j], gbuf0[j + 128], gbuf0[j + 256],
                               gbuf0[j + 384], cst);
            h0h[j] = (h16)h;
        }
        __syncthreads();  // B2: h0h ready

        if (grp == 1) {  // Wih1 @ h0n (+bias1)
            float gA, gB;
            dot2rows(h0h, wA, wB, biasA, biasB, gA, gB);
            g1a[r0] = gA;
            g1a[r1] = gB;
        }
        __syncthreads();  // B3: g1a ready

        if (t < HID) {  // act1 + fused fc reduction
            float h = lstm_act(g1a[t] + pgi, g1a[t + 128] + pgf,
                               g1a[t + 256] + pgg, g1a[t + 384] + pgo, cst);
            h1h[t] = (h16)h;
            float part = fcwj * h;
#pragma unroll
            for (int off = 32; off >= 1; off >>= 1)
                part += __shfl_down(part, off, 64);
            if ((t & 63) == 0) ypart[t >> 6] = part;
        }
        __syncthreads();  // B4: h1h + ypart ready
    }

    if (t == 0) outb[HSTEPS - 1] = ypart[0] + ypart[1] + fcb_;
}

extern "C" void kernel_launch(void* const* d_in, const int* in_sizes, int n_in,
                              void* d_out, int out_size, void* d_ws,
                              size_t ws_size, hipStream_t stream) {
    const float* y0 = (const float*)d_in[0];
    const float* h0 = (const float*)d_in[1];
    const float* c0 = (const float*)d_in[2];
    const float* Wih0 = (const float*)d_in[3];
    const float* Whh0 = (const float*)d_in[4];
    const float* bih0 = (const float*)d_in[5];
    const float* bhh0 = (const float*)d_in[6];
    const float* Wih1 = (const float*)d_in[7];
    const float* Whh1 = (const float*)d_in[8];
    const float* bih1 = (const float*)d_in[9];
    const float* bhh1 = (const float*)d_in[10];
    const float* fcw = (const float*)d_in[11];
    const float* fcb = (const float*)d_in[12];
    float* out = (float*)d_out;

    lstm2_kernel<<<dim3(BATCH), dim3(NTHR), 0, stream>>>(
        y0, h0, c0, Wih0, Whh0, bih0, bhh0, Wih1, Whh1, bih1, bhh1, fcw, fcb,
        out);
}

// Round 3
// 14163.397 us; speedup vs baseline: 1.0395x; 1.0395x over previous
//
#include <hip/hip_runtime.h>

#define HSTEPS 8640
#define HID 128
#define BATCH 16
#define NTHR 512
#define YRING 192

typedef _Float16 h16;
typedef __attribute__((ext_vector_type(2))) _Float16 h16x2;
typedef __attribute__((ext_vector_type(8))) _Float16 h16x8;

static __device__ __forceinline__ float fdot2f(h16x2 a, h16x2 b, float c) {
    return __builtin_amdgcn_fdot2(a, b, c, false);
}
static __device__ __forceinline__ float sigm(float x) {
    return __builtin_amdgcn_rcpf(1.0f + __expf(-x));
}
static __device__ __forceinline__ float tanh_f(float x) {
    float ax = __builtin_fabsf(x);
    float ee = __expf(2.0f * ax);
    float r = 1.0f - 2.0f * __builtin_amdgcn_rcpf(ee + 1.0f);
    return __builtin_copysignf(r, x);
}

// ---- DPP helpers (VALU-only cross-lane) ----
template <int CTRL>
static __device__ __forceinline__ float dppmov(float x) {
    return __int_as_float(__builtin_amdgcn_mov_dpp(__float_as_int(x), CTRL, 0xF, 0xF, false));
}
// sum of 8-periodic values (lane pattern l&7) -> every lane holds the sum
static __device__ __forceinline__ float sum8(float x) {
    x += dppmov<0x121>(x);  // row_ror:1
    x += dppmov<0x122>(x);  // row_ror:2
    x += dppmov<0x124>(x);  // row_ror:4
    return x;
}
// full wave64 sum -> total lands in lane 63
static __device__ __forceinline__ float red_wave(float x) {
    x += dppmov<0x121>(x);
    x += dppmov<0x122>(x);
    x += dppmov<0x124>(x);
    x += dppmov<0x128>(x);  // row_ror:8 -> every lane = its 16-row sum
    float t1 = __int_as_float(__builtin_amdgcn_update_dpp(
        0, __float_as_int(x), 0x142 /*row_bcast15*/, 0xA, 0xF, false));
    x += t1;  // rows 1,3 += rows 0,2
    float t2 = __int_as_float(__builtin_amdgcn_update_dpp(
        0, __float_as_int(x), 0x143 /*row_bcast31*/, 0xC, 0xF, false));
    x += t2;  // rows 2,3 += rows 0+1  => lane63 = wave total
    return x;
}

// quad-local LSTM activation: lane holds gate-type q (= t&3) of element e.
// Gathers the 4 gate values inside the quad via quad_perm, updates c, returns h.
static __device__ __forceinline__ float quad_act(float G, int q, float& c) {
    float n1 = dppmov<0xB1>(G);  // value from lane q^1
    float n2 = dppmov<0x4E>(G);  // q^2
    float n3 = dppmov<0x1B>(G);  // q^3
    bool b0 = (q & 1) != 0, b1 = (q & 2) != 0;
    float gi = b1 ? (b0 ? n3 : n2) : (b0 ? n1 : G);
    float gf = b1 ? (b0 ? n2 : n3) : (b0 ? G : n1);
    float gg = b1 ? (b0 ? n1 : G) : (b0 ? n3 : n2);
    float go = b1 ? (b0 ? G : n1) : (b0 ? n2 : n3);
    float si = sigm(gi), sf = sigm(gf), so = sigm(go);
    float tg = tanh_f(gg);
    c = __builtin_fmaf(sf, c, si * tg);
    return so * tanh_f(c);
}

#define R16(F) F(0) F(1) F(2) F(3) F(4) F(5) F(6) F(7) F(8) F(9) F(10) F(11) F(12) F(13) F(14) F(15)

// One block per batch element; 512 threads = 8 waves.
// Thread t: q = t&3 (gate type), e = t>>2 (element); owns row 128q+e of
// Whh0, Wih1, Whh1 as 48 NAMED h16x8 registers (192 VGPRs, spill-proof).
// 2 barriers/step; acts in-register via quad_perm; y staged in LDS ring.
__global__ __launch_bounds__(NTHR, 2) void lstm2_kernel(
    const float* __restrict__ y0, const float* __restrict__ h0in,
    const float* __restrict__ c0in, const float* __restrict__ Wih0,
    const float* __restrict__ Whh0, const float* __restrict__ bih0,
    const float* __restrict__ bhh0, const float* __restrict__ Wih1,
    const float* __restrict__ Whh1, const float* __restrict__ bih1,
    const float* __restrict__ bhh1, const float* __restrict__ fcw,
    const float* __restrict__ fcb, float* __restrict__ out) {
    const int b = blockIdx.x;
    const int t = threadIdx.x;
    const int q = t & 3;
    const int e = t >> 2;          // element 0..127
    const int row = (q << 7) | e;  // gate row 128q+e

    __shared__ __align__(16) h16 h0s[2][HID];  // parity-buffered h (layer 0)
    __shared__ __align__(16) h16 h1s[2][HID];  // parity-buffered h (layer 1)
    __shared__ float ypartbuf[8];              // per-wave fc partials
    __shared__ float ybuf[YRING];              // output ring

    // ---- weights: 48 named h16x8 registers ----
#define DW0(i) h16x8 w0_##i;
#define DW1(i) h16x8 w1_##i;
#define DW2(i) h16x8 w2_##i;
    R16(DW0) R16(DW1) R16(DW2)

    {
        const float* rp = Whh0 + row * HID;
#define LW0(i)                                                             \
    {                                                                      \
        float4 a_ = *(const float4*)(rp + i * 8);                          \
        float4 b_ = *(const float4*)(rp + i * 8 + 4);                      \
        w0_##i = h16x8{(h16)a_.x, (h16)a_.y, (h16)a_.z, (h16)a_.w,         \
                       (h16)b_.x, (h16)b_.y, (h16)b_.z, (h16)b_.w};        \
    }
        R16(LW0)
        rp = Wih1 + row * HID;
#define LW1(i)                                                             \
    {                                                                      \
        float4 a_ = *(const float4*)(rp + i * 8);                          \
        float4 b_ = *(const float4*)(rp + i * 8 + 4);                      \
        w1_##i = h16x8{(h16)a_.x, (h16)a_.y, (h16)a_.z, (h16)a_.w,         \
                       (h16)b_.x, (h16)b_.y, (h16)b_.z, (h16)b_.w};        \
    }
        R16(LW1)
        rp = Whh1 + row * HID;
#define LW2(i)                                                             \
    {                                                                      \
        float4 a_ = *(const float4*)(rp + i * 8);                          \
        float4 b_ = *(const float4*)(rp + i * 8 + 4);                      \
        w2_##i = h16x8{(h16)a_.x, (h16)a_.y, (h16)a_.z, (h16)a_.w,         \
                       (h16)b_.x, (h16)b_.y, (h16)b_.z, (h16)b_.w};        \
    }
        R16(LW2)
    }

    const float bias0 = bih0[row] + bhh0[row];
    const float bias1 = bih1[row] + bhh1[row];
    const float wih0t = Wih0[row];
    const float fcb_ = fcb[0];
    const float fcw_q0 = (q == 0) ? fcw[e] : 0.0f;

    float c0 = c0in[b * HID + e];             // layer-0 cell state (quad-replicated)
    float c1 = c0in[(BATCH + b) * HID + e];   // layer-1 cell state

    if (q == 0) {
        h0s[0][e] = (h16)h0in[b * HID + e];
        h1s[0][e] = (h16)h0in[(BATCH + b) * HID + e];
    }
    if (t < 8) ypartbuf[t] = (t == 0) ? (y0[b] - fcb_) : 0.0f;
    __syncthreads();

    float* outb = out + (size_t)b * HSTEPS;
    int p = 0;
    int ys = 0;
    int flush_at = YRING;

#pragma unroll 1
    for (int s = 0; s < HSTEPS; ++s) {
        // ---- assemble y = fc output of previous step (all lanes) ----
        float y = sum8(ypartbuf[t & 7]) + fcb_;
        if (s > 0) {
            if (t == 0) ybuf[ys] = y;  // y(s-1)
            ys = (ys == YRING - 1) ? 0 : ys + 1;
        }

        // ---- phase A: gates0 = Whh0 @ h0_prev + Wih0*y + bias0 ----
        const h16* h0p = &h0s[p][0];
        float acc0 = __builtin_fmaf(wih0t, y, bias0);
        float acc1 = 0.f, acc2 = 0.f, acc3 = 0.f;
#define DA(i)                                                               \
    {                                                                       \
        h16x8 hv = *(const h16x8*)(h0p + i * 8);                            \
        acc0 = fdot2f(h16x2{w0_##i[0], w0_##i[1]}, h16x2{hv[0], hv[1]}, acc0); \
        acc1 = fdot2f(h16x2{w0_##i[2], w0_##i[3]}, h16x2{hv[2], hv[3]}, acc1); \
        acc2 = fdot2f(h16x2{w0_##i[4], w0_##i[5]}, h16x2{hv[4], hv[5]}, acc2); \
        acc3 = fdot2f(h16x2{w0_##i[6], w0_##i[7]}, h16x2{hv[6], hv[7]}, acc3); \
    }
        R16(DA)
        float G = (acc0 + acc1) + (acc2 + acc3);
        float h0n = quad_act(G, q, c0);
        if (q == 0) h0s[p ^ 1][e] = (h16)h0n;
        __syncthreads();  // B1: h0 new ready

        // ---- periodic output flush (uniform branch, 1/192 steps) ----
        if (s == flush_at) {
            if (t < YRING) outb[flush_at - YRING + t] = ybuf[t];
            flush_at += YRING;
        }

        // ---- phase B: gates1 = Wih1 @ h0n + Whh1 @ h1_prev + bias1 ----
        const h16* h0np = &h0s[p ^ 1][0];
        const h16* h1p = &h1s[p][0];
        acc0 = bias1;
        acc1 = acc2 = acc3 = 0.f;
#define DB0(i)                                                              \
    {                                                                       \
        h16x8 hv = *(const h16x8*)(h0np + i * 8);                           \
        acc0 = fdot2f(h16x2{w1_##i[0], w1_##i[1]}, h16x2{hv[0], hv[1]}, acc0); \
        acc1 = fdot2f(h16x2{w1_##i[2], w1_##i[3]}, h16x2{hv[2], hv[3]}, acc1); \
        acc2 = fdot2f(h16x2{w1_##i[4], w1_##i[5]}, h16x2{hv[4], hv[5]}, acc2); \
        acc3 = fdot2f(h16x2{w1_##i[6], w1_##i[7]}, h16x2{hv[6], hv[7]}, acc3); \
    }
        R16(DB0)
#define DB1(i)                                                              \
    {                                                                       \
        h16x8 hv = *(const h16x8*)(h1p + i * 8);                            \
        acc0 = fdot2f(h16x2{w2_##i[0], w2_##i[1]}, h16x2{hv[0], hv[1]}, acc0); \
        acc1 = fdot2f(h16x2{w2_##i[2], w2_##i[3]}, h16x2{hv[2], hv[3]}, acc1); \
        acc2 = fdot2f(h16x2{w2_##i[4], w2_##i[5]}, h16x2{hv[4], hv[5]}, acc2); \
        acc3 = fdot2f(h16x2{w2_##i[6], w2_##i[7]}, h16x2{hv[6], hv[7]}, acc3); \
    }
        R16(DB1)
        G = (acc0 + acc1) + (acc2 + acc3);
        float h1n = quad_act(G, q, c1);
        if (q == 0) h1s[p ^ 1][e] = (h16)h1n;

        // ---- fused fc: per-wave partial via DPP, one LDS write ----
        float part = red_wave(fcw_q0 * h1n);
        if ((t & 63) == 63) ypartbuf[t >> 6] = part;

        p ^= 1;
        __syncthreads();  // B2: h1/ypart ready for next step
    }

    // ---- tail: assemble y(8639), final flush ----
    float y = sum8(ypartbuf[t & 7]) + fcb_;
    if (t == 0) ybuf[YRING - 1] = y;
    __syncthreads();
    if (t < YRING) outb[HSTEPS - YRING + t] = ybuf[t];
}

extern "C" void kernel_launch(void* const* d_in, const int* in_sizes, int n_in,
                              void* d_out, int out_size, void* d_ws,
                              size_t ws_size, hipStream_t stream) {
    const float* y0 = (const float*)d_in[0];
    const float* h0 = (const float*)d_in[1];
    const float* c0 = (const float*)d_in[2];
    const float* Wih0 = (const float*)d_in[3];
    const float* Whh0 = (const float*)d_in[4];
    const float* bih0 = (const float*)d_in[5];
    const float* bhh0 = (const float*)d_in[6];
    const float* Wih1 = (const float*)d_in[7];
    const float* Whh1 = (const float*)d_in[8];
    const float* bih1 = (const float*)d_in[9];
    const float* bhh1 = (const float*)d_in[10];
    const float* fcw = (const float*)d_in[11];
    const float* fcb = (const float*)d_in[12];
    float* out = (float*)d_out;

    lstm2_kernel<<<dim3(BATCH), dim3(NTHR), 0, stream>>>(
        y0, h0, c0, Wih0, Whh0, bih0, bhh0, Wih1, Whh1, bih1, bhh1, fcw, fcb,
        out);
}